// Round 19
// baseline (157.473 us; speedup 1.0000x reference)
//
#include <hip/hip_runtime.h>

#define N_NODES 50000
#define N_EDGES 800000
#define DIM 128
#define NB 391            // buckets of 128 dst nodes
#define CAP 2560          // padded capacity per bucket
#define NCH 7             // src chunks for csr chunk-sort
#define BIN_CHUNK 4096
#define BIN_BLOCKS 196
#define PREP_BLOCKS 64    // Wt pack blocks
#define GEMM_TILES 782    // ceil(50000/64)
#define AGG_BLOCKS 3125   // 50000 / 16

typedef unsigned int uint;
typedef unsigned short ushort;
typedef __attribute__((ext_vector_type(8))) __bf16 bf16x8;
typedef __attribute__((ext_vector_type(4))) float f32x4;

__device__ __forceinline__ uint f2bf(float f) {
    uint u = __float_as_uint(f);
    return (u + 0x7FFFu + ((u >> 16) & 1u)) >> 16;
}
__device__ __forceinline__ float2 bf2f2(uint u) {
    return make_float2(__uint_as_float(u << 16), __uint_as_float(u & 0xFFFF0000u));
}

// ---------------- K1: bin (blocks<196) || W^T bf16 pack (rest) ----------------
// bincursor memset-0; count-based reservation: base = b*CAP + old_count.

__global__ __launch_bounds__(256) void binprep_kernel(const int* __restrict__ ei,
                                                      int* __restrict__ bincursor,
                                                      uint* __restrict__ pairs,
                                                      const float* __restrict__ W1,
                                                      const float* __restrict__ W2,
                                                      uint* __restrict__ Wt1,
                                                      uint* __restrict__ Wt2) {
    if (blockIdx.x >= BIN_BLOCKS) {
        int idx = (blockIdx.x - BIN_BLOCKS) * 256 + threadIdx.x;  // 0..16383
        const float* W = (idx < 8192) ? W1 : W2;
        uint* Wt = (idx < 8192) ? Wt1 : Wt2;
        int i = idx & 8191;
        int n = i >> 6, k2 = i & 63;
        Wt[i] = f2bf(W[(2 * k2) * DIM + n]) | (f2bf(W[(2 * k2 + 1) * DIM + n]) << 16);
        return;
    }
    __shared__ int lh[NB];
    __shared__ int lbase[NB];
    int t = threadIdx.x;
    int eb = blockIdx.x * BIN_CHUNK;

    for (int b = t; b < NB; b += 256) lh[b] = 0;
    __syncthreads();

    int s_reg[16], d_reg[16];
#pragma unroll
    for (int i = 0; i < 16; ++i) {
        int e = eb + i * 256 + t;
        if (e < N_EDGES) {
            s_reg[i] = ei[e];
            d_reg[i] = ei[N_EDGES + e];
            atomicAdd(&lh[d_reg[i] >> 7], 1);
        } else {
            d_reg[i] = -1;
        }
    }
    __syncthreads();

    for (int b = t; b < NB; b += 256) {
        int c = lh[b];
        lbase[b] = c ? (b * CAP + atomicAdd(&bincursor[b], c)) : 0;
    }
    __syncthreads();
    for (int b = t; b < NB; b += 256) lh[b] = 0;
    __syncthreads();

#pragma unroll
    for (int i = 0; i < 16; ++i) {
        int d = d_reg[i];
        if (d >= 0) {
            int bin = d >> 7;
            int r = atomicAdd(&lh[bin], 1);
            pairs[lbase[bin] + r] = ((uint)s_reg[i] << 7) | (uint)(d & 127);
        }
    }
}

// ---------------- K2: fillpack — CSR build (chunk-sorted) + dinv + xb pack ----------------

__global__ __launch_bounds__(256) void fillpack_kernel(const uint* __restrict__ pairs,
                                                       const int* __restrict__ bincursor,
                                                       int* __restrict__ rowbeg,
                                                       int* __restrict__ rowend,
                                                       float* __restrict__ dinv,
                                                       int* __restrict__ csr_src,
                                                       const float* __restrict__ x,
                                                       uint* __restrict__ xb) {
    __shared__ int cnt[128 * 8];
    __shared__ int nsum[128];
    __shared__ int nbase[128];
    __shared__ float sdinv[128];
    int t = threadIdx.x;
    int blk = blockIdx.x;
    int bs = blk * CAP;
    int be = bs + bincursor[blk];

    for (int i = t; i < 128 * 8; i += 256) cnt[i] = 0;
    __syncthreads();

    for (int p = bs + t; p < be; p += 256) {
        uint pr = pairs[p];
        atomicAdd(&cnt[(pr & 127u) * 8 + (pr >> 20)], 1);
    }
    __syncthreads();

    if (t < 128) {
        int s = 0;
#pragma unroll
        for (int c = 0; c < NCH; ++c) s += cnt[t * 8 + c];
        nsum[t] = s;
        nbase[t] = s;
    }
    __syncthreads();
#pragma unroll
    for (int off = 1; off < 128; off <<= 1) {
        int v = (t < 128 && t >= off) ? nbase[t - off] : 0;
        __syncthreads();
        if (t < 128) nbase[t] += v;
        __syncthreads();
    }

    if (t < 128) {
        int deg = nsum[t];
        int ex = nbase[t] - deg;
        int node = blk * 128 + t;
        float di = rsqrtf((float)deg + 1.0f);
        sdinv[t] = di;
        if (node < N_NODES) {
            rowbeg[node] = bs + ex;
            rowend[node] = bs + nbase[t];
            dinv[node] = di;
        }
        int run = ex;
#pragma unroll
        for (int c = 0; c < NCH; ++c) {
            int v = cnt[t * 8 + c];
            cnt[t * 8 + c] = run;
            run += v;
        }
    }
    __syncthreads();

    // scatter csr
    for (int p = bs + t; p < be; p += 256) {
        uint pr = pairs[p];
        int r = atomicAdd(&cnt[(pr & 127u) * 8 + (pr >> 20)], 1);
        csr_src[bs + r] = (int)(pr >> 7);
    }

    // pack xb = bf16(dinv * x) for own 128 nodes
    for (int i = t; i < 128 * 64; i += 256) {
        int row = i >> 6;
        int u = i & 63;
        int node = blk * 128 + row;
        if (node < N_NODES) {
            float2 xv = *(const float2*)(x + (size_t)node * DIM + 2 * u);
            float d = sdinv[row];
            xb[(size_t)node * 64 + u] = f2bf(xv.x * d) | (f2bf(xv.y * d) << 16);
        }
    }
}

// ---------------- aggS: pure gather-sum of bf16 rows -> fp32 rows ----------------
// 4 nodes/wave, 16 lanes/node, 8-deep MLP. agg[d] = self + sum_{s in N(d)}.

__global__ __launch_bounds__(256) void aggS_kernel(const int* __restrict__ rowbeg,
                                                   const int* __restrict__ rowend,
                                                   const int* __restrict__ csr_src,
                                                   const uint* __restrict__ Hb,
                                                   float* __restrict__ aggF) {
    int gt = blockIdx.x * 256 + threadIdx.x;
    int wave = gt >> 6;
    int lane = gt & 63;
    int grp = lane >> 4;
    int li = lane & 15;
    int node = wave * 4 + grp;  // 12500 waves * 4 = 50000, exact

    int beg = rowbeg[node];
    int end = rowend[node];

    const uint4* H4 = (const uint4*)Hb;
    float a0, a1, a2, a3, a4, a5, a6, a7;
    {
        uint4 su = H4[(size_t)node * 16 + li];
        float2 v0 = bf2f2(su.x), v1 = bf2f2(su.y), v2 = bf2f2(su.z), v3 = bf2f2(su.w);
        a0 = v0.x; a1 = v0.y; a2 = v1.x; a3 = v1.y;
        a4 = v2.x; a5 = v2.y; a6 = v3.x; a7 = v3.y;
    }

#define ADD8(u)                                                                   \
    {                                                                             \
        float2 v0 = bf2f2(u.x), v1 = bf2f2(u.y), v2 = bf2f2(u.z), v3 = bf2f2(u.w);\
        a0 += v0.x; a1 += v0.y; a2 += v1.x; a3 += v1.y;                           \
        a4 += v2.x; a5 += v2.y; a6 += v3.x; a7 += v3.y;                           \
    }

    int e = beg;
    for (; e + 7 < end; e += 8) {
        int s[8];
#pragma unroll
        for (int i = 0; i < 8; ++i) s[i] = csr_src[e + i];
        uint4 u[8];
#pragma unroll
        for (int i = 0; i < 8; ++i) u[i] = H4[(size_t)s[i] * 16 + li];
#pragma unroll
        for (int i = 0; i < 8; ++i) ADD8(u[i]);
    }
    if (e + 3 < end) {
        int s[4];
#pragma unroll
        for (int i = 0; i < 4; ++i) s[i] = csr_src[e + i];
        uint4 u[4];
#pragma unroll
        for (int i = 0; i < 4; ++i) u[i] = H4[(size_t)s[i] * 16 + li];
#pragma unroll
        for (int i = 0; i < 4; ++i) ADD8(u[i]);
        e += 4;
    }
    for (; e < end; ++e) {
        uint4 u = H4[(size_t)csr_src[e] * 16 + li];
        ADD8(u);
    }
#undef ADD8

    float4* O4 = (float4*)(aggF + (size_t)node * DIM);
    O4[li * 2] = make_float4(a0, a1, a2, a3);
    O4[li * 2 + 1] = make_float4(a4, a5, a6, a7);
}

// ---------------- gemmA: out1b = bf16( dinv * relu( dinv*(aggA@W1) + b1 ) ) ----------------

__global__ __launch_bounds__(256) void gemmA_kernel(const float* __restrict__ aggF,
                                                    const uint* __restrict__ Wt,
                                                    const float* __restrict__ dinv,
                                                    const float* __restrict__ b1,
                                                    uint* __restrict__ out1b) {
    int t = threadIdx.x;
    int wv = t >> 6;
    int l = t & 63;
    int col = l & 15;
    int g = l >> 4;
    int base = blockIdx.x * 64;
    int grow = base + wv * 16 + col;
    int ar = grow > N_NODES - 1 ? N_NODES - 1 : grow;

    bf16x8 af[4];
    const float4* Xr = (const float4*)(aggF + (size_t)ar * DIM);
#pragma unroll
    for (int kk = 0; kk < 4; ++kk) {
        float4 x0 = Xr[kk * 8 + g * 2];
        float4 x1 = Xr[kk * 8 + g * 2 + 1];
        uint4 p;
        p.x = f2bf(x0.x) | (f2bf(x0.y) << 16);
        p.y = f2bf(x0.z) | (f2bf(x0.w) << 16);
        p.z = f2bf(x1.x) | (f2bf(x1.y) << 16);
        p.w = f2bf(x1.z) | (f2bf(x1.w) << 16);
        af[kk] = __builtin_bit_cast(bf16x8, p);
    }

    const uint4* Wr = (const uint4*)Wt;
    f32x4 acc[8];
#pragma unroll
    for (int n = 0; n < 8; ++n) acc[n] = (f32x4){0.f, 0.f, 0.f, 0.f};

#pragma unroll
    for (int n = 0; n < 8; ++n) {
        const uint4* wrow = Wr + (size_t)(n * 16 + col) * 16;
#pragma unroll
        for (int kk = 0; kk < 4; ++kk) {
            bf16x8 bf = __builtin_bit_cast(bf16x8, wrow[kk * 4 + g]);
            acc[n] = __builtin_amdgcn_mfma_f32_16x16x32_bf16(af[kk], bf, acc[n], 0, 0, 0);
        }
    }

    float bb[8];
#pragma unroll
    for (int n = 0; n < 8; ++n) bb[n] = b1[n * 16 + col];

#pragma unroll
    for (int j = 0; j < 4; ++j) {
        int row = base + wv * 16 + g * 4 + j;
        if (row < N_NODES) {
            float di = dinv[row];
            ushort* hrow = (ushort*)(out1b + (size_t)row * 64);
#pragma unroll
            for (int n = 0; n < 8; ++n) {
                float o = fmaxf(di * acc[n][j] + bb[n], 0.f);
                hrow[n * 16 + col] = (ushort)f2bf(di * o);
            }
        }
    }
}

// ---------------- gemmB: out = relu( dinv*(aggB@W2) + b2 + x ) (fp32) ----------------

__global__ __launch_bounds__(256) void gemmB_kernel(const float* __restrict__ aggF,
                                                    const uint* __restrict__ Wt,
                                                    const float* __restrict__ dinv,
                                                    const float* __restrict__ b2,
                                                    const float* __restrict__ x,
                                                    float* __restrict__ out) {
    int t = threadIdx.x;
    int wv = t >> 6;
    int l = t & 63;
    int col = l & 15;
    int g = l >> 4;
    int base = blockIdx.x * 64;
    int grow = base + wv * 16 + col;
    int ar = grow > N_NODES - 1 ? N_NODES - 1 : grow;

    bf16x8 af[4];
    const float4* Xr = (const float4*)(aggF + (size_t)ar * DIM);
#pragma unroll
    for (int kk = 0; kk < 4; ++kk) {
        float4 x0 = Xr[kk * 8 + g * 2];
        float4 x1 = Xr[kk * 8 + g * 2 + 1];
        uint4 p;
        p.x = f2bf(x0.x) | (f2bf(x0.y) << 16);
        p.y = f2bf(x0.z) | (f2bf(x0.w) << 16);
        p.z = f2bf(x1.x) | (f2bf(x1.y) << 16);
        p.w = f2bf(x1.z) | (f2bf(x1.w) << 16);
        af[kk] = __builtin_bit_cast(bf16x8, p);
    }

    const uint4* Wr = (const uint4*)Wt;
    f32x4 acc[8];
#pragma unroll
    for (int n = 0; n < 8; ++n) acc[n] = (f32x4){0.f, 0.f, 0.f, 0.f};

#pragma unroll
    for (int n = 0; n < 8; ++n) {
        const uint4* wrow = Wr + (size_t)(n * 16 + col) * 16;
#pragma unroll
        for (int kk = 0; kk < 4; ++kk) {
            bf16x8 bf = __builtin_bit_cast(bf16x8, wrow[kk * 4 + g]);
            acc[n] = __builtin_amdgcn_mfma_f32_16x16x32_bf16(af[kk], bf, acc[n], 0, 0, 0);
        }
    }

    float bb[8];
#pragma unroll
    for (int n = 0; n < 8; ++n) bb[n] = b2[n * 16 + col];

#pragma unroll
    for (int j = 0; j < 4; ++j) {
        int row = base + wv * 16 + g * 4 + j;
        if (row < N_NODES) {
            float di = dinv[row];
            const float* xr = x + (size_t)row * DIM;
            float* orow = out + (size_t)row * DIM;
#pragma unroll
            for (int n = 0; n < 8; ++n) {
                int c = n * 16 + col;
                orow[c] = fmaxf(di * acc[n][j] + bb[n] + xr[c], 0.f);
            }
        }
    }
}

// ---------------- launch ----------------

extern "C" void kernel_launch(void* const* d_in, const int* in_sizes, int n_in,
                              void* d_out, int out_size, void* d_ws, size_t ws_size,
                              hipStream_t stream) {
    const float* x = (const float*)d_in[0];
    const int* edge_index = (const int*)d_in[1];
    const float* W1 = (const float*)d_in[2];
    const float* b1 = (const float*)d_in[3];
    const float* W2 = (const float*)d_in[4];
    const float* b2 = (const float*)d_in[5];
    float* out = (float*)d_out;

    char* ws = (char*)d_ws;
    int*   bincursor = (int*)(ws + 0);               // 1.6 KB
    float* dinv      = (float*)(ws + (256 << 10));   // 200 KB
    int*   rowbeg    = (int*)(ws + (512 << 10));     // 200 KB
    int*   rowend    = (int*)(ws + (768 << 10));     // 200 KB
    int*   csr_src   = (int*)(ws + (1 << 20));       // 4.0 MB (padded)
    uint*  pairs     = (uint*)(ws + (5 << 20));      // 4.0 MB (packed, padded)
    uint*  xb        = (uint*)(ws + (9 << 20));      // 12.8 MB bf16(dinv*x)
    uint*  out1b     = (uint*)(ws + (22 << 20));     // 12.8 MB bf16(dinv*out1)
    float* aggF      = (float*)(ws + (35 << 20));    // 25.6 MB fp32 agg (reused)
    uint*  Wt1       = (uint*)(ws + (61 << 20));     // 32 KB
    uint*  Wt2       = (uint*)(ws + (61 << 20) + (64 << 10));  // 32 KB

    // K0: zero bucket counters
    hipMemsetAsync(bincursor, 0, NB * sizeof(int), stream);
    // K1: bin || Wt pack
    binprep_kernel<<<BIN_BLOCKS + PREP_BLOCKS, 256, 0, stream>>>(edge_index, bincursor, pairs,
                                                                 W1, W2, Wt1, Wt2);
    // K2: CSR build + dinv + xb pack
    fillpack_kernel<<<NB, 256, 0, stream>>>(pairs, bincursor, rowbeg, rowend, dinv, csr_src, x,
                                            xb);
    // K3: aggA = gather-sum(xb) -> fp32
    aggS_kernel<<<AGG_BLOCKS, 256, 0, stream>>>(rowbeg, rowend, csr_src, xb, aggF);
    // K4: out1b = bf16(dinv * relu(dinv*(aggA@W1) + b1))
    gemmA_kernel<<<GEMM_TILES, 256, 0, stream>>>(aggF, Wt1, dinv, b1, out1b);
    // K5: aggB = gather-sum(out1b) -> fp32 (reuses aggF)
    aggS_kernel<<<AGG_BLOCKS, 256, 0, stream>>>(rowbeg, rowend, csr_src, out1b, aggF);
    // K6: out = relu(dinv*(aggB@W2) + b2 + x)
    gemmB_kernel<<<GEMM_TILES, 256, 0, stream>>>(aggF, Wt2, dinv, b2, x, out);
}

// Round 20
// 120.870 us; speedup vs baseline: 1.3028x; 1.3028x over previous
//
#include <hip/hip_runtime.h>

#define N_NODES 50000
#define N_EDGES 800000
#define DIM 128
#define NB 391          // buckets of 128 dst nodes
#define CAP 2560        // padded capacity per bucket
#define NCH 7           // src chunks of 8192 nodes
#define BIN_CHUNK 4096
#define BIN_BLOCKS 196
#define GEMM_TILES 782  // ceil(50000/64)
#define AGG_TILES 3125  // 50000 / 16 nodes per block (exact)

typedef unsigned int uint;
typedef unsigned short ushort;
typedef __attribute__((ext_vector_type(8))) __bf16 bf16x8;
typedef __attribute__((ext_vector_type(4))) float f32x4;

__device__ __forceinline__ uint f2bf(float f) {
    uint u = __float_as_uint(f);
    return (u + 0x7FFFu + ((u >> 16) & 1u)) >> 16;
}
__device__ __forceinline__ float2 bf2f2(uint u) {
    return make_float2(__uint_as_float(u << 16), __uint_as_float(u & 0xFFFF0000u));
}

// ---------------- prep: W^T bf16 pre-pack + bucket cursor init ----------------

__global__ __launch_bounds__(256) void prep_kernel(const float* __restrict__ W1,
                                                   const float* __restrict__ W2,
                                                   uint* __restrict__ Wt1,
                                                   uint* __restrict__ Wt2,
                                                   int* __restrict__ bincursor) {
    int idx = blockIdx.x * 256 + threadIdx.x;
    if (idx < 16384) {
        const float* W = (idx < 8192) ? W1 : W2;
        uint* Wt = (idx < 8192) ? Wt1 : Wt2;
        int i = idx & 8191;
        int n = i >> 6, k2 = i & 63;
        Wt[i] = f2bf(W[(2 * k2) * DIM + n]) | (f2bf(W[(2 * k2 + 1) * DIM + n]) << 16);
    } else {
        int b = idx - 16384;
        if (b < NB) bincursor[b] = b * CAP;
    }
}

// ---------------- gemm1: 64-row tile from global fp32, unscaled bf16 out ----------------

__device__ __forceinline__ void gemm_tile64(const float* __restrict__ X,
                                            const uint* __restrict__ Wt, int base,
                                            uint* __restrict__ Hout) {
    int t = threadIdx.x;
    int wv = t >> 6;
    int l = t & 63;
    int col = l & 15;
    int g = l >> 4;
    int grow = base + wv * 16 + col;
    int ar = grow > N_NODES - 1 ? N_NODES - 1 : grow;

    bf16x8 af[4];
    const float4* Xr = (const float4*)(X + (size_t)ar * DIM);
#pragma unroll
    for (int kk = 0; kk < 4; ++kk) {
        float4 x0 = Xr[kk * 8 + g * 2];
        float4 x1 = Xr[kk * 8 + g * 2 + 1];
        uint4 p;
        p.x = f2bf(x0.x) | (f2bf(x0.y) << 16);
        p.y = f2bf(x0.z) | (f2bf(x0.w) << 16);
        p.z = f2bf(x1.x) | (f2bf(x1.y) << 16);
        p.w = f2bf(x1.z) | (f2bf(x1.w) << 16);
        af[kk] = __builtin_bit_cast(bf16x8, p);
    }

    const uint4* Wr = (const uint4*)Wt;
    f32x4 acc[8];
#pragma unroll
    for (int n = 0; n < 8; ++n) acc[n] = (f32x4){0.f, 0.f, 0.f, 0.f};

#pragma unroll
    for (int n = 0; n < 8; ++n) {
        const uint4* wrow = Wr + (size_t)(n * 16 + col) * 16;
#pragma unroll
        for (int kk = 0; kk < 4; ++kk) {
            bf16x8 bf = __builtin_bit_cast(bf16x8, wrow[kk * 4 + g]);
            acc[n] = __builtin_amdgcn_mfma_f32_16x16x32_bf16(af[kk], bf, acc[n], 0, 0, 0);
        }
    }

#pragma unroll
    for (int j = 0; j < 4; ++j) {
        int row = base + wv * 16 + g * 4 + j;
        if (row < N_NODES) {
            ushort* hrow = (ushort*)(Hout + (size_t)row * 64);
#pragma unroll
            for (int n = 0; n < 8; ++n) hrow[n * 16 + col] = (ushort)f2bf(acc[n][j]);
        }
    }
}

// ---------------- gemm2: 16-row tile from swizzled LDS, wave = 32-col strip ----------------

__device__ __forceinline__ void gemm_tile16_lds(const uint* __restrict__ sB,
                                                const uint* __restrict__ Wt,
                                                const float* __restrict__ dinv, int base,
                                                uint* __restrict__ Hout) {
    int t = threadIdx.x;
    int wv = t >> 6;   // wave = 32-col strip
    int l = t & 63;
    int col = l & 15;
    int g = l >> 4;
    int lr = col;      // A row in tile (16 rows shared by all waves)

    bf16x8 af[4];
#pragma unroll
    for (int kk = 0; kk < 4; ++kk) {
        int ui = lr * 64 + ((kk * 16 + g * 4) ^ ((lr & 7) << 2));
        af[kk] = __builtin_bit_cast(bf16x8, *(const uint4*)&sB[ui]);
    }

    const uint4* Wr = (const uint4*)Wt;
    f32x4 acc[2];
#pragma unroll
    for (int nn = 0; nn < 2; ++nn) acc[nn] = (f32x4){0.f, 0.f, 0.f, 0.f};

#pragma unroll
    for (int nn = 0; nn < 2; ++nn) {
        int n = wv * 2 + nn;
        const uint4* wrow = Wr + (size_t)(n * 16 + col) * 16;
#pragma unroll
        for (int kk = 0; kk < 4; ++kk) {
            bf16x8 bf = __builtin_bit_cast(bf16x8, wrow[kk * 4 + g]);
            acc[nn] = __builtin_amdgcn_mfma_f32_16x16x32_bf16(af[kk], bf, acc[nn], 0, 0, 0);
        }
    }

#pragma unroll
    for (int j = 0; j < 4; ++j) {
        int row = base + g * 4 + j;  // rows 0..15, always valid (50000 % 16 == 0)
        float di = dinv[row];
        ushort* hrow = (ushort*)(Hout + (size_t)row * 64);
#pragma unroll
        for (int nn = 0; nn < 2; ++nn) {
            int n = wv * 2 + nn;
            hrow[n * 16 + col] = (ushort)f2bf(acc[nn][j] * di);
        }
    }
}

// ---------------- K2: bin (blocks<196) || gemm1 unscaled (rest) ----------------

__global__ __launch_bounds__(256) void bin_gemm1_kernel(const int* __restrict__ ei,
                                                        int* __restrict__ bincursor,
                                                        uint* __restrict__ pairs,
                                                        const float* __restrict__ x,
                                                        const uint* __restrict__ Wt1,
                                                        uint* __restrict__ Hs) {
    if (blockIdx.x >= BIN_BLOCKS) {
        gemm_tile64(x, Wt1, (blockIdx.x - BIN_BLOCKS) * 64, Hs);
        return;
    }
    __shared__ int lh[NB];
    __shared__ int lbase[NB];
    int t = threadIdx.x;
    int eb = blockIdx.x * BIN_CHUNK;

    for (int b = t; b < NB; b += 256) lh[b] = 0;
    __syncthreads();

    int s_reg[16], d_reg[16];
#pragma unroll
    for (int i = 0; i < 16; ++i) {
        int e = eb + i * 256 + t;
        if (e < N_EDGES) {
            s_reg[i] = ei[e];
            d_reg[i] = ei[N_EDGES + e];
            atomicAdd(&lh[d_reg[i] >> 7], 1);
        } else {
            d_reg[i] = -1;
        }
    }
    __syncthreads();

    for (int b = t; b < NB; b += 256) {
        int c = lh[b];
        lbase[b] = c ? atomicAdd(&bincursor[b], c) : 0;
    }
    __syncthreads();
    for (int b = t; b < NB; b += 256) lh[b] = 0;
    __syncthreads();

#pragma unroll
    for (int i = 0; i < 16; ++i) {
        int d = d_reg[i];
        if (d >= 0) {
            int bin = d >> 7;
            int r = atomicAdd(&lh[bin], 1);
            pairs[lbase[bin] + r] = ((uint)s_reg[i] << 7) | (uint)(d & 127);
        }
    }
}

// ---------------- fill2: per-bucket CSR build, chunk-sorted per node ----------------

__global__ __launch_bounds__(256) void fill2_kernel(const uint* __restrict__ pairs,
                                                    const int* __restrict__ bincursor,
                                                    int* __restrict__ rowbeg,
                                                    int* __restrict__ rowend,
                                                    float* __restrict__ dinv,
                                                    int* __restrict__ csr_src) {
    __shared__ int cnt[128 * 8];
    __shared__ int nsum[128];
    __shared__ int nbase[128];
    int t = threadIdx.x;
    int blk = blockIdx.x;
    int bs = blk * CAP;
    int be = bincursor[blk];

    for (int i = t; i < 128 * 8; i += 256) cnt[i] = 0;
    __syncthreads();

    for (int p = bs + t; p < be; p += 256) {
        uint pr = pairs[p];
        atomicAdd(&cnt[(pr & 127u) * 8 + (pr >> 20)], 1);
    }
    __syncthreads();

    if (t < 128) {
        int s = 0;
#pragma unroll
        for (int c = 0; c < NCH; ++c) s += cnt[t * 8 + c];
        nsum[t] = s;
        nbase[t] = s;
    }
    __syncthreads();
#pragma unroll
    for (int off = 1; off < 128; off <<= 1) {
        int v = (t < 128 && t >= off) ? nbase[t - off] : 0;
        __syncthreads();
        if (t < 128) nbase[t] += v;
        __syncthreads();
    }

    if (t < 128) {
        int ex = nbase[t] - nsum[t];
        int node = blk * 128 + t;
        if (node < N_NODES) {
            rowbeg[node] = bs + ex;
            rowend[node] = bs + nbase[t];
            dinv[node] = rsqrtf((float)nsum[t] + 1.0f);
        }
        int run = ex;
#pragma unroll
        for (int c = 0; c < NCH; ++c) {
            int v = cnt[t * 8 + c];
            cnt[t * 8 + c] = run;
            run += v;
        }
    }
    __syncthreads();

    for (int p = bs + t; p < be; p += 256) {
        uint pr = pairs[p];
        int r = atomicAdd(&cnt[(pr & 127u) * 8 + (pr >> 20)], 1);
        csr_src[bs + r] = (int)(pr >> 7);
    }
}

// ---------------- agg core: one (node, li) slab; 8-deep MLP ----------------

template <bool DSRC>
__device__ __forceinline__ void agg_node(const int* __restrict__ rowbeg,
                                         const int* __restrict__ rowend,
                                         const int* __restrict__ csr_src,
                                         const uint* __restrict__ Hs,
                                         const float* __restrict__ dinv,
                                         const float* __restrict__ bias, int node, int li,
                                         float r[8]) {
    int beg = rowbeg[node];
    int end = rowend[node];
    float di = dinv[node];

    const uint4* H4 = (const uint4*)Hs;
    float a0, a1, a2, a3, a4, a5, a6, a7;
    {
        uint4 su = H4[(size_t)node * 16 + li];
        float2 v0 = bf2f2(su.x), v1 = bf2f2(su.y), v2 = bf2f2(su.z), v3 = bf2f2(su.w);
        float sf = DSRC ? di : 1.0f;
        a0 = sf * v0.x; a1 = sf * v0.y; a2 = sf * v1.x; a3 = sf * v1.y;
        a4 = sf * v2.x; a5 = sf * v2.y; a6 = sf * v3.x; a7 = sf * v3.y;
    }

#define ADDF8(u, f)                                                               \
    {                                                                             \
        float2 v0 = bf2f2(u.x), v1 = bf2f2(u.y), v2 = bf2f2(u.z), v3 = bf2f2(u.w);\
        a0 += f * v0.x; a1 += f * v0.y; a2 += f * v1.x; a3 += f * v1.y;           \
        a4 += f * v2.x; a5 += f * v2.y; a6 += f * v3.x; a7 += f * v3.y;           \
    }

    int e = beg;
    for (; e + 7 < end; e += 8) {
        int s[8];
#pragma unroll
        for (int i = 0; i < 8; ++i) s[i] = csr_src[e + i];
        uint4 u[8];
#pragma unroll
        for (int i = 0; i < 8; ++i) u[i] = H4[(size_t)s[i] * 16 + li];
        float f[8];
#pragma unroll
        for (int i = 0; i < 8; ++i) f[i] = DSRC ? dinv[s[i]] : 1.0f;
#pragma unroll
        for (int i = 0; i < 8; ++i) ADDF8(u[i], f[i]);
    }
    if (e + 3 < end) {
        int s[4];
#pragma unroll
        for (int i = 0; i < 4; ++i) s[i] = csr_src[e + i];
        uint4 u[4];
#pragma unroll
        for (int i = 0; i < 4; ++i) u[i] = H4[(size_t)s[i] * 16 + li];
        float f[4];
#pragma unroll
        for (int i = 0; i < 4; ++i) f[i] = DSRC ? dinv[s[i]] : 1.0f;
#pragma unroll
        for (int i = 0; i < 4; ++i) ADDF8(u[i], f[i]);
        e += 4;
    }
    for (; e < end; ++e) {
        int s = csr_src[e];
        uint4 u = H4[(size_t)s * 16 + li];
        float f = DSRC ? dinv[s] : 1.0f;
        ADDF8(u, f);
    }
#undef ADDF8

    const float4* B4 = (const float4*)bias;
    float4 bb0 = B4[li * 2], bb1 = B4[li * 2 + 1];
    r[0] = a0 * di + bb0.x; r[1] = a1 * di + bb0.y;
    r[2] = a2 * di + bb0.z; r[3] = a3 * di + bb0.w;
    r[4] = a4 * di + bb1.x; r[5] = a5 * di + bb1.y;
    r[6] = a6 * di + bb1.z; r[7] = a7 * di + bb1.w;
}

// ---------------- K4: fused agg1 (relu -> swizzled LDS) + gemm2 (from LDS), 16-node tiles ----------------

__global__ __launch_bounds__(256) void aggemm_kernel(const int* __restrict__ rowbeg,
                                                     const int* __restrict__ rowend,
                                                     const int* __restrict__ csr_src,
                                                     const uint* __restrict__ Hs,
                                                     const float* __restrict__ dinv,
                                                     const float* __restrict__ b1,
                                                     const uint* __restrict__ Wt2,
                                                     uint* __restrict__ Hs2) {
    __shared__ uint sB[16 * 64];  // 16 rows x 128 bf16, XOR-swizzled, 4 KB
    int t = threadIdx.x;
    int wv = t >> 6;
    int lane = t & 63;
    int grp = lane >> 4;
    int li = lane & 15;
    int base = blockIdx.x * 16;

    // phase A: aggregate 16 nodes (one per (wv,grp)), relu, pack bf16 into swizzled LDS
    {
        int row = wv * 4 + grp;  // 0..15
        int node = base + row;   // always < 50000 (exact division)
        float r[8];
        agg_node<true>(rowbeg, rowend, csr_src, Hs, dinv, b1, node, li, r);
        uint4 o;
        o.x = f2bf(fmaxf(r[0], 0.f)) | (f2bf(fmaxf(r[1], 0.f)) << 16);
        o.y = f2bf(fmaxf(r[2], 0.f)) | (f2bf(fmaxf(r[3], 0.f)) << 16);
        o.z = f2bf(fmaxf(r[4], 0.f)) | (f2bf(fmaxf(r[5], 0.f)) << 16);
        o.w = f2bf(fmaxf(r[6], 0.f)) | (f2bf(fmaxf(r[7], 0.f)) << 16);
        int ui = row * 64 + ((li * 4) ^ ((row & 7) << 2));
        *(uint4*)&sB[ui] = o;
    }
    __syncthreads();

    // phase B: conv2 MFMA 16-row tile from LDS, dinv-scaled bf16 out
    gemm_tile16_lds(sB, Wt2, dinv, base, Hs2);
}

// ---------------- K5: agg2 (+bias +residual, relu, fp32 out) ----------------

__global__ __launch_bounds__(256) void agg2_kernel(const int* __restrict__ rowbeg,
                                                   const int* __restrict__ rowend,
                                                   const int* __restrict__ csr_src,
                                                   const uint* __restrict__ Hs2,
                                                   const float* __restrict__ dinv,
                                                   const float* __restrict__ b2,
                                                   const float* __restrict__ resid,
                                                   float* __restrict__ out) {
    int wave = (int)((blockIdx.x * (size_t)blockDim.x + threadIdx.x) >> 6);
    int lane = threadIdx.x & 63;
    int grp = lane >> 4;
    int li = lane & 15;
    int node = wave * 4 + grp;  // 12500 waves * 4 = 50000 exact

    float r[8];
    agg_node<false>(rowbeg, rowend, csr_src, Hs2, dinv, b2, node, li, r);

    const float4* R4 = (const float4*)(resid + (size_t)node * DIM);
    float4 x0 = R4[li * 2], x1 = R4[li * 2 + 1];
    r[0] += x0.x; r[1] += x0.y; r[2] += x0.z; r[3] += x0.w;
    r[4] += x1.x; r[5] += x1.y; r[6] += x1.z; r[7] += x1.w;

    float4* O4 = (float4*)(out + (size_t)node * DIM);
    O4[li * 2] = make_float4(fmaxf(r[0], 0.f), fmaxf(r[1], 0.f), fmaxf(r[2], 0.f),
                             fmaxf(r[3], 0.f));
    O4[li * 2 + 1] = make_float4(fmaxf(r[4], 0.f), fmaxf(r[5], 0.f), fmaxf(r[6], 0.f),
                                 fmaxf(r[7], 0.f));
}

// ---------------- launch ----------------

extern "C" void kernel_launch(void* const* d_in, const int* in_sizes, int n_in,
                              void* d_out, int out_size, void* d_ws, size_t ws_size,
                              hipStream_t stream) {
    const float* x = (const float*)d_in[0];
    const int* edge_index = (const int*)d_in[1];
    const float* W1 = (const float*)d_in[2];
    const float* b1 = (const float*)d_in[3];
    const float* W2 = (const float*)d_in[4];
    const float* b2 = (const float*)d_in[5];
    float* out = (float*)d_out;

    char* ws = (char*)d_ws;
    int*   bincursor = (int*)(ws + 0);              // 1.6 KB
    float* dinv      = (float*)(ws + (64 << 10));   // 200 KB
    int*   rowbeg    = (int*)(ws + (320 << 10));    // 200 KB
    int*   rowend    = (int*)(ws + (576 << 10));    // 200 KB
    int*   csr_src   = (int*)(ws + (1 << 20));      // 4.0 MB (padded)
    uint*  pairs     = (uint*)(ws + (6 << 20));     // 4.0 MB (packed, padded)
    uint*  Hs        = (uint*)(ws + (11 << 20));    // 12.8 MB (bf16, conv1 h unscaled)
    uint*  Hs2       = (uint*)(ws + (24 << 20));    // 12.8 MB (bf16, conv2 h scaled)
    uint*  Wt1       = (uint*)(ws + (37 << 20));    // 32 KB
    uint*  Wt2       = (uint*)(ws + (37 << 20) + (64 << 10));  // 32 KB

    // K1: Wt pack + cursor init
    prep_kernel<<<66, 256, 0, stream>>>(W1, W2, Wt1, Wt2, bincursor);
    // K2: bin || gemm1 (unscaled h -> Hs)
    bin_gemm1_kernel<<<BIN_BLOCKS + GEMM_TILES, 256, 0, stream>>>(edge_index, bincursor, pairs,
                                                                  x, Wt1, Hs);
    // K3: CSR build (chunk-sorted) + dinv
    fill2_kernel<<<NB, 256, 0, stream>>>(pairs, bincursor, rowbeg, rowend, dinv, csr_src);
    // K4: fused agg1 + gemm2 -> Hs2 (16-node tiles = agg2's proven gather shape)
    aggemm_kernel<<<AGG_TILES, 256, 0, stream>>>(rowbeg, rowend, csr_src, Hs, dinv, b1, Wt2,
                                                 Hs2);
    // K5: agg2 + residual -> out
    agg2_kernel<<<3125, 256, 0, stream>>>(rowbeg, rowend, csr_src, Hs2, dinv, b2, x, out);
}